// Round 3
// baseline (259.107 us; speedup 1.0000x reference)
//
#include <hip/hip_runtime.h>
#include <hip/hip_bf16.h>

namespace {

constexpr int S  = 2048;
constexpr int D  = 64;
constexpr int NHEAD = 32;        // B*H
constexpr int QT = 64;           // q rows per block (4 waves x 16)
constexpr int NT = 64;           // k rows per chunk
constexpr int NCH = S / NT;      // 32
constexpr int NTILE = NHEAD * NCH;   // 1024
constexpr size_t TILE_B = 64 * 128;  // 8 KB bf16 tile image

using bf16x8 = __attribute__((ext_vector_type(8))) short;
using bf16x4 = __attribute__((ext_vector_type(4))) short;
using f32x4  = __attribute__((ext_vector_type(4))) float;

__device__ __forceinline__ short f2bf(float f) {
  union { float f; unsigned u; } x; x.f = f;
  unsigned r = x.u + 0x7fffu + ((x.u >> 16) & 1u);
  return (short)(r >> 16);
}

__device__ __forceinline__ void gload_lds16(const void* g, void* l) {
  __builtin_amdgcn_global_load_lds(
      (const __attribute__((address_space(1))) unsigned int*)g,
      (__attribute__((address_space(3))) unsigned int*)l, 16, 0, 0);
}

#define FENCE() asm volatile("" ::: "memory")

// ============================================================================
// Prep: Q -> bf16 prescaled (x0.125), K -> swizzled [n][d] tile images,
// V -> swizzled transposed [d][n] tile images. One block per (head, chunk).
// Image layout == byte-exact LDS tile: row*128 + ((byte) ^ ((row&7)<<4)).
// ============================================================================
__global__ __launch_bounds__(256) void attn_prep(
    const float* __restrict__ Q, const float* __restrict__ K,
    const float* __restrict__ V, short* __restrict__ Qi,
    char* __restrict__ Ki, char* __restrict__ Vi)
{
  __shared__ float Vl[64][68];
  const int bid = blockIdx.x;              // head*32 + nt
  const int head = bid >> 5, nt = bid & 31;
  const int tid = threadIdx.x;
  const size_t sbase = (size_t)head * S * D + (size_t)nt * NT * D;

  { // Q slice rows nt*64..+64, prescale 1/sqrt(D)=0.125 (exact)
    const int row = tid >> 2, c = (tid & 3) * 16;
    const float* qp = Q + sbase + row * D + c;
    float4 a = ((const float4*)qp)[0], b = ((const float4*)qp)[1];
    float4 e = ((const float4*)qp)[2], d = ((const float4*)qp)[3];
    bf16x8 h0, h1;
    h0[0]=f2bf(a.x*.125f); h0[1]=f2bf(a.y*.125f); h0[2]=f2bf(a.z*.125f); h0[3]=f2bf(a.w*.125f);
    h0[4]=f2bf(b.x*.125f); h0[5]=f2bf(b.y*.125f); h0[6]=f2bf(b.z*.125f); h0[7]=f2bf(b.w*.125f);
    h1[0]=f2bf(e.x*.125f); h1[1]=f2bf(e.y*.125f); h1[2]=f2bf(e.z*.125f); h1[3]=f2bf(e.w*.125f);
    h1[4]=f2bf(d.x*.125f); h1[5]=f2bf(d.y*.125f); h1[6]=f2bf(d.z*.125f); h1[7]=f2bf(d.w*.125f);
    short* dst = Qi + ((size_t)head * S + nt * NT + row) * D + c;
    *(bf16x8*)dst = h0; *(bf16x8*)(dst + 8) = h1;
  }
  { // K tile image (swizzled rows)
#pragma unroll
    for (int it = 0; it < 2; ++it) {
      const int w = tid + it * 256, n = w >> 3, seg = w & 7;
      const float* kp = K + sbase + n * D + seg * 8;
      float4 a = ((const float4*)kp)[0], b = ((const float4*)kp)[1];
      bf16x8 h;
      h[0]=f2bf(a.x); h[1]=f2bf(a.y); h[2]=f2bf(a.z); h[3]=f2bf(a.w);
      h[4]=f2bf(b.x); h[5]=f2bf(b.y); h[6]=f2bf(b.z); h[7]=f2bf(b.w);
      *(bf16x8*)(Ki + (size_t)bid * TILE_B + n * 128 + ((seg * 16) ^ ((n & 7) << 4))) = h;
    }
  }
  { // V: LDS fp32 transpose staging
    const int n = tid >> 2, c = (tid & 3) * 16;
    const float* vp = V + sbase + n * D + c;
    float4 a = ((const float4*)vp)[0], b = ((const float4*)vp)[1];
    float4 e = ((const float4*)vp)[2], d = ((const float4*)vp)[3];
    *(float4*)&Vl[n][c]      = a; *(float4*)&Vl[n][c + 4]  = b;
    *(float4*)&Vl[n][c + 8]  = e; *(float4*)&Vl[n][c + 12] = d;
  }
  __syncthreads();
  { // V^T tile image (swizzled rows, row = d)
#pragma unroll
    for (int it = 0; it < 2; ++it) {
      const int w = tid + it * 256, d = w >> 3, seg = w & 7;
      bf16x8 h;
#pragma unroll
      for (int i = 0; i < 8; ++i) h[i] = f2bf(Vl[seg * 8 + i][d]);
      *(bf16x8*)(Vi + (size_t)bid * TILE_B + d * 128 + ((seg * 16) ^ ((d & 7) << 4))) = h;
    }
  }
}

// ============================================================================
// Kernel 1: flash-style out + row-sum reciprocals. K/V staged from the
// pre-swizzled images via global_load_lds (16B), double-buffered with
// counted vmcnt + raw barriers (loads stay in flight across barriers).
// ============================================================================
__global__ __launch_bounds__(256) void attn_out(
    const short* __restrict__ Qi, const char* __restrict__ Ki,
    const char* __restrict__ Vi, float* __restrict__ Out,
    float* __restrict__ Lv)
{
  __shared__ char Kl[2][TILE_B];
  __shared__ char Vt[2][TILE_B];
  __shared__ short Pl[4][16 * 72];

  const int tid = threadIdx.x, wave = tid >> 6, lane = tid & 63;
  const int g = lane >> 4, r = lane & 15;
  const int b = blockIdx.x;
  const int wg = ((b & 7) << 7) | (b >> 3);   // XCD-chunked swizzle (1024 = 8*128)
  const int head = wg >> 5, qt = wg & 31;
  const int qrow0 = qt * QT + wave * 16;

  bf16x8 qa[2];
  {
    const short* qp = Qi + ((size_t)head * S + qrow0 + r) * D + g * 8;
    qa[0] = *(const bf16x8*)qp;
    qa[1] = *(const bf16x8*)(qp + 32);
  }

  const char* kt0 = Ki + (size_t)(head * NCH) * TILE_B + wave * 2048 + lane * 16;
  const char* vt0 = Vi + (size_t)(head * NCH) * TILE_B + wave * 2048 + lane * 16;

  auto stage = [&](int buf, int nt) {
    const char* ks = kt0 + (size_t)nt * TILE_B;
    const char* vs = vt0 + (size_t)nt * TILE_B;
    char* kd = Kl[buf] + wave * 2048;
    char* vd = Vt[buf] + wave * 2048;
    gload_lds16(ks, kd);
    gload_lds16(ks + 1024, kd + 1024);
    gload_lds16(vs, vd);
    gload_lds16(vs + 1024, vd + 1024);
  };

  float lsum[4] = {0.f, 0.f, 0.f, 0.f};
  f32x4 acc[4];
#pragma unroll
  for (int dt = 0; dt < 4; ++dt) acc[dt] = f32x4{0.f, 0.f, 0.f, 0.f};
  short* Pw = Pl[wave];

  stage(0, 0);
  for (int nt = 0; nt < NCH; ++nt) {
    const int cur = nt & 1;
    if (nt + 1 < NCH) {
      stage(cur ^ 1, nt + 1);
      asm volatile("s_waitcnt vmcnt(4)" ::: "memory");  // cur landed, next in flight
    } else {
      asm volatile("s_waitcnt vmcnt(0)" ::: "memory");
    }
    FENCE(); __builtin_amdgcn_s_barrier(); FENCE();

    f32x4 s[4];
#pragma unroll
    for (int t = 0; t < 4; ++t) s[t] = f32x4{0.f, 0.f, 0.f, 0.f};
#pragma unroll
    for (int f = 0; f < 2; ++f) {
#pragma unroll
      for (int t = 0; t < 4; ++t) {
        bf16x8 kb = *(const bf16x8*)(Kl[cur] + (t * 16 + r) * 128 +
                        ((f * 64 + g * 16) ^ ((r & 7) << 4)));
        s[t] = __builtin_amdgcn_mfma_f32_16x16x32_bf16(qa[f], kb, s[t], 0, 0, 0);
      }
    }

#pragma unroll
    for (int t = 0; t < 4; ++t) {
#pragma unroll
      for (int j = 0; j < 4; ++j) {
        float p = __expf(s[t][j]);
        lsum[j] += p;
        Pw[(4 * g + j) * 72 + t * 16 + r] = f2bf(p);
      }
    }
    asm volatile("s_waitcnt lgkmcnt(0)" ::: "memory");
    __builtin_amdgcn_sched_barrier(0);

#pragma unroll
    for (int kc = 0; kc < 2; ++kc) {
      bf16x8 pa = *(const bf16x8*)((char*)Pw + r * 144 + kc * 64 + g * 16);
#pragma unroll
      for (int dt = 0; dt < 4; ++dt) {
        bf16x8 vb = *(const bf16x8*)(Vt[cur] + (dt * 16 + r) * 128 +
                        ((kc * 64 + g * 16) ^ ((r & 7) << 4)));
        acc[dt] = __builtin_amdgcn_mfma_f32_16x16x32_bf16(pa, vb, acc[dt], 0, 0, 0);
      }
    }
    FENCE(); __builtin_amdgcn_s_barrier(); FENCE();  // buf[cur] reads done
  }

#pragma unroll
  for (int m = 1; m < 16; m <<= 1)
#pragma unroll
    for (int j = 0; j < 4; ++j)
      lsum[j] += __shfl_xor(lsum[j], m, 64);
  float linv[4];
#pragma unroll
  for (int j = 0; j < 4; ++j) linv[j] = 1.f / lsum[j];

  const size_t obase = (size_t)head * S * D;
#pragma unroll
  for (int dt = 0; dt < 4; ++dt)
#pragma unroll
    for (int j = 0; j < 4; ++j)
      Out[obase + (size_t)(qrow0 + 4 * g + j) * D + dt * 16 + r] = acc[dt][j] * linv[j];

  if (r == 0) {
#pragma unroll
    for (int j = 0; j < 4; ++j)
      Lv[head * S + qrow0 + 4 * g + j] = linv[j];
  }
}

// ============================================================================
// Kernel 2: attn-weight streamer. Swapped QK^T (A=K, B=Q); K A-frags loaded
// per-lane directly from the swizzled image (L2-resident). No LDS, no
// barriers, 2-deep software pipeline. Write-BW-bound by design.
// ============================================================================
__global__ __launch_bounds__(256) void attn_wr(
    const short* __restrict__ Qi, const char* __restrict__ Ki,
    float* __restrict__ Aw, const float* __restrict__ Lv)
{
  const int tid = threadIdx.x, wave = tid >> 6, lane = tid & 63;
  const int g = lane >> 4, r = lane & 15;
  const int b = blockIdx.x;
  const int wg = ((b & 7) << 7) | (b >> 3);
  const int head = wg >> 5, qt = wg & 31;
  const int q = qt * QT + wave * 16 + r;

  bf16x8 qb[2];
  {
    const short* qp = Qi + ((size_t)head * S + q) * D + g * 8;
    qb[0] = *(const bf16x8*)qp;
    qb[1] = *(const bf16x8*)(qp + 32);
  }
  const float linv = Lv[head * S + q];
  float* arow = Aw + (size_t)head * S * S + (size_t)q * S;

  int loff[8];
#pragma unroll
  for (int f = 0; f < 2; ++f)
#pragma unroll
    for (int t = 0; t < 4; ++t)
      loff[f * 4 + t] = (t * 16 + r) * 128 + ((f * 64 + g * 16) ^ ((r & 7) << 4));
  const char* kbase = Ki + (size_t)(head * NCH) * TILE_B;

  bf16x8 fa[8], fb[8];
  auto load8 = [&](bf16x8 (&fr)[8], int nt) {
    const char* p = kbase + (size_t)nt * TILE_B;
#pragma unroll
    for (int i = 0; i < 8; ++i) fr[i] = *(const bf16x8*)(p + loff[i]);
  };
  auto comp = [&](const bf16x8 (&fr)[8], int nt) {
    f32x4 s[4];
#pragma unroll
    for (int t = 0; t < 4; ++t) s[t] = f32x4{0.f, 0.f, 0.f, 0.f};
#pragma unroll
    for (int f = 0; f < 2; ++f)
#pragma unroll
      for (int t = 0; t < 4; ++t)
        s[t] = __builtin_amdgcn_mfma_f32_16x16x32_bf16(fr[f * 4 + t], qb[f], s[t], 0, 0, 0);
    // C: col(lane&15)=q, row(4g+j)=key t*16+4g+j -> float4 store
#pragma unroll
    for (int t = 0; t < 4; ++t) {
      float4 pv;
      pv.x = __expf(s[t][0]) * linv;
      pv.y = __expf(s[t][1]) * linv;
      pv.z = __expf(s[t][2]) * linv;
      pv.w = __expf(s[t][3]) * linv;
      *(float4*)(arow + nt * NT + t * 16 + 4 * g) = pv;
    }
  };

  load8(fa, 0);
  for (int nt = 0; nt < NCH; nt += 2) {
    load8(fb, nt + 1);
    comp(fa, nt);
    if (nt + 2 < NCH) load8(fa, nt + 2);
    comp(fb, nt + 1);
  }
}

// ============================================================================
// Fallback (ws too small): round-2 kernels, staging fp32->bf16 in-kernel.
// ============================================================================
__global__ __launch_bounds__(256) void attn_out_fb(
    const float* __restrict__ Q, const float* __restrict__ K,
    const float* __restrict__ V, float* __restrict__ Out,
    float* __restrict__ Lv)
{
  __shared__ short Klb[2][64 * 64];
  __shared__ short Vtb[2][64 * 64];
  __shared__ short Pl[4][16 * 72];

  const int tid = threadIdx.x, wave = tid >> 6, lane = tid & 63;
  const int g = lane >> 4, r = lane & 15;
  const int head = blockIdx.x >> 5, qt = blockIdx.x & 31;
  const size_t base = (size_t)head * S * D;
  const int qrow0 = qt * QT + wave * 16;

  bf16x8 qa[2];
  {
    const float* qp = Q + base + (size_t)(qrow0 + r) * D + g * 8;
#pragma unroll
    for (int f = 0; f < 2; ++f) {
      float4 a = *(const float4*)(qp + f * 32);
      float4 bb = *(const float4*)(qp + f * 32 + 4);
      bf16x8 t;
      t[0]=f2bf(a.x*.125f); t[1]=f2bf(a.y*.125f); t[2]=f2bf(a.z*.125f); t[3]=f2bf(a.w*.125f);
      t[4]=f2bf(bb.x*.125f); t[5]=f2bf(bb.y*.125f); t[6]=f2bf(bb.z*.125f); t[7]=f2bf(bb.w*.125f);
      qa[f] = t;
    }
  }
  const int sn = tid >> 2, sseg = tid & 3, tbr = tid >> 4, tbc = tid & 15;
  const float* kp0 = K + base + (size_t)sn * D + sseg * 16;
  const float* vp0 = V + base + (size_t)(tbr * 4) * D + tbc * 4;
  float4 kr[4], vr[4];
  auto loadKV = [&](int nt) {
    const float* kp = kp0 + (size_t)nt * NT * D;
    kr[0]=((const float4*)kp)[0]; kr[1]=((const float4*)kp)[1];
    kr[2]=((const float4*)kp)[2]; kr[3]=((const float4*)kp)[3];
    const float* vp = vp0 + (size_t)nt * NT * D;
    vr[0]=*(const float4*)(vp); vr[1]=*(const float4*)(vp+D);
    vr[2]=*(const float4*)(vp+2*D); vr[3]=*(const float4*)(vp+3*D);
  };
  auto stageKV = [&](int buf) {
    bf16x8 h0, h1;
    h0[0]=f2bf(kr[0].x); h0[1]=f2bf(kr[0].y); h0[2]=f2bf(kr[0].z); h0[3]=f2bf(kr[0].w);
    h0[4]=f2bf(kr[1].x); h0[5]=f2bf(kr[1].y); h0[6]=f2bf(kr[1].z); h0[7]=f2bf(kr[1].w);
    h1[0]=f2bf(kr[2].x); h1[1]=f2bf(kr[2].y); h1[2]=f2bf(kr[2].z); h1[3]=f2bf(kr[2].w);
    h1[4]=f2bf(kr[3].x); h1[5]=f2bf(kr[3].y); h1[6]=f2bf(kr[3].z); h1[7]=f2bf(kr[3].w);
    char* rowp = (char*)Klb[buf] + sn * 128;
    *(bf16x8*)(rowp + ((sseg * 32)      ^ ((sn & 7) << 4))) = h0;
    *(bf16x8*)(rowp + ((sseg * 32 + 16) ^ ((sn & 7) << 4))) = h1;
#pragma unroll
    for (int dl = 0; dl < 4; ++dl) {
      int d = tbc * 4 + dl;
      bf16x4 w;
      w[0]=f2bf(((const float*)&vr[0])[dl]); w[1]=f2bf(((const float*)&vr[1])[dl]);
      w[2]=f2bf(((const float*)&vr[2])[dl]); w[3]=f2bf(((const float*)&vr[3])[dl]);
      *(bf16x4*)((char*)Vtb[buf] + d * 128 + ((tbr * 8) ^ ((d & 7) << 4))) = w;
    }
  };
  loadKV(0); stageKV(0);
  float lsum[4] = {0.f,0.f,0.f,0.f};
  f32x4 acc[4];
#pragma unroll
  for (int dt = 0; dt < 4; ++dt) acc[dt] = f32x4{0.f,0.f,0.f,0.f};
  short* Pw = Pl[wave];
  for (int nt = 0; nt < NCH; ++nt) {
    const int cur = nt & 1;
    __syncthreads();
    if (nt + 1 < NCH) loadKV(nt + 1);
    f32x4 s[4];
#pragma unroll
    for (int t = 0; t < 4; ++t) s[t] = f32x4{0.f,0.f,0.f,0.f};
#pragma unroll
    for (int f = 0; f < 2; ++f)
#pragma unroll
      for (int t = 0; t < 4; ++t) {
        bf16x8 kb = *(const bf16x8*)((char*)Klb[cur] + (t*16+r)*128 + ((f*64+g*16) ^ ((r&7)<<4)));
        s[t] = __builtin_amdgcn_mfma_f32_16x16x32_bf16(qa[f], kb, s[t], 0, 0, 0);
      }
#pragma unroll
    for (int t = 0; t < 4; ++t)
#pragma unroll
      for (int j = 0; j < 4; ++j) {
        float p = __expf(s[t][j]);
        lsum[j] += p;
        Pw[(4*g+j)*72 + t*16 + r] = f2bf(p);
      }
    asm volatile("s_waitcnt lgkmcnt(0)" ::: "memory");
    __builtin_amdgcn_sched_barrier(0);
#pragma unroll
    for (int kc = 0; kc < 2; ++kc) {
      bf16x8 pa = *(const bf16x8*)((char*)Pw + r*144 + kc*64 + g*16);
#pragma unroll
      for (int dt = 0; dt < 4; ++dt) {
        bf16x8 vb = *(const bf16x8*)((char*)Vtb[cur] + (dt*16+r)*128 + ((kc*64+g*16) ^ ((r&7)<<4)));
        acc[dt] = __builtin_amdgcn_mfma_f32_16x16x32_bf16(pa, vb, acc[dt], 0, 0, 0);
      }
    }
    if (nt + 1 < NCH) stageKV(cur ^ 1);
  }
#pragma unroll
  for (int m = 1; m < 16; m <<= 1)
#pragma unroll
    for (int j = 0; j < 4; ++j) lsum[j] += __shfl_xor(lsum[j], m, 64);
  float linv[4];
#pragma unroll
  for (int j = 0; j < 4; ++j) linv[j] = 1.f / lsum[j];
#pragma unroll
  for (int dt = 0; dt < 4; ++dt)
#pragma unroll
    for (int j = 0; j < 4; ++j)
      Out[base + (size_t)(qrow0 + 4*g + j) * D + dt*16 + r] = acc[dt][j] * linv[j];
  if (r == 0) {
#pragma unroll
    for (int j = 0; j < 4; ++j) Lv[head * S + qrow0 + 4*g + j] = linv[j];
  }
}

__global__ __launch_bounds__(256) void attn_wr_fb(
    const float* __restrict__ Q, const float* __restrict__ K,
    float* __restrict__ Aw, const float* __restrict__ Lv)
{
  __shared__ short Klb[2][64 * 64];
  const int tid = threadIdx.x, wave = tid >> 6, lane = tid & 63;
  const int g = lane >> 4, r = lane & 15;
  const int head = blockIdx.x >> 5, qt = blockIdx.x & 31;
  const size_t base = (size_t)head * S * D;
  float* att = Aw + (size_t)head * S * S;
  const int q = qt * QT + wave * 16 + r;
  bf16x8 qb[2];
  {
    const float* qp = Q + base + (size_t)q * D + g * 8;
#pragma unroll
    for (int f = 0; f < 2; ++f) {
      float4 a = *(const float4*)(qp + f * 32);
      float4 bb = *(const float4*)(qp + f * 32 + 4);
      bf16x8 t;
      t[0]=f2bf(a.x*.125f); t[1]=f2bf(a.y*.125f); t[2]=f2bf(a.z*.125f); t[3]=f2bf(a.w*.125f);
      t[4]=f2bf(bb.x*.125f); t[5]=f2bf(bb.y*.125f); t[6]=f2bf(bb.z*.125f); t[7]=f2bf(bb.w*.125f);
      qb[f] = t;
    }
  }
  const float linv = Lv[head * S + q];
  float* arow = att + (size_t)q * S;
  const int sn = tid >> 2, sseg = tid & 3;
  const float* kp0 = K + base + (size_t)sn * D + sseg * 16;
  float4 kr[4];
  auto loadK = [&](int nt) {
    const float* kp = kp0 + (size_t)nt * NT * D;
    kr[0]=((const float4*)kp)[0]; kr[1]=((const float4*)kp)[1];
    kr[2]=((const float4*)kp)[2]; kr[3]=((const float4*)kp)[3];
  };
  auto stageK = [&](int buf) {
    bf16x8 h0, h1;
    h0[0]=f2bf(kr[0].x); h0[1]=f2bf(kr[0].y); h0[2]=f2bf(kr[0].z); h0[3]=f2bf(kr[0].w);
    h0[4]=f2bf(kr[1].x); h0[5]=f2bf(kr[1].y); h0[6]=f2bf(kr[1].z); h0[7]=f2bf(kr[1].w);
    h1[0]=f2bf(kr[2].x); h1[1]=f2bf(kr[2].y); h1[2]=f2bf(kr[2].z); h1[3]=f2bf(kr[2].w);
    h1[4]=f2bf(kr[3].x); h1[5]=f2bf(kr[3].y); h1[6]=f2bf(kr[3].z); h1[7]=f2bf(kr[3].w);
    char* rowp = (char*)Klb[buf] + sn * 128;
    *(bf16x8*)(rowp + ((sseg * 32)      ^ ((sn & 7) << 4))) = h0;
    *(bf16x8*)(rowp + ((sseg * 32 + 16) ^ ((sn & 7) << 4))) = h1;
  };
  loadK(0); stageK(0);
  for (int nt = 0; nt < NCH; ++nt) {
    const int cur = nt & 1;
    __syncthreads();
    if (nt + 1 < NCH) loadK(nt + 1);
    f32x4 s[4];
#pragma unroll
    for (int t = 0; t < 4; ++t) s[t] = f32x4{0.f,0.f,0.f,0.f};
#pragma unroll
    for (int f = 0; f < 2; ++f)
#pragma unroll
      for (int t = 0; t < 4; ++t) {
        bf16x8 ka = *(const bf16x8*)((char*)Klb[cur] + (t*16+r)*128 + ((f*64+g*16) ^ ((r&7)<<4)));
        s[t] = __builtin_amdgcn_mfma_f32_16x16x32_bf16(ka, qb[f], s[t], 0, 0, 0);
      }
#pragma unroll
    for (int t = 0; t < 4; ++t) {
      float4 pv;
      pv.x = __expf(s[t][0]) * linv;
      pv.y = __expf(s[t][1]) * linv;
      pv.z = __expf(s[t][2]) * linv;
      pv.w = __expf(s[t][3]) * linv;
      *(float4*)(arow + nt * NT + t * 16 + 4 * g) = pv;
    }
    if (nt + 1 < NCH) stageK(cur ^ 1);
  }
}

} // namespace

extern "C" void kernel_launch(void* const* d_in, const int* in_sizes, int n_in,
                              void* d_out, int out_size, void* d_ws, size_t ws_size,
                              hipStream_t stream) {
  const float* q = (const float*)d_in[0];
  const float* k = (const float*)d_in[1];
  const float* v = (const float*)d_in[2];
  float* out = (float*)d_out;
  float* aw  = out + (size_t)NHEAD * S * D;

  const size_t KI_B = (size_t)NTILE * TILE_B;        // 8 MB
  const size_t NEED = 3 * KI_B + NHEAD * S * 4;      // Ki+Vi+Qi+Lv = 25.4 MB

  if (ws_size >= NEED) {
    char*  Ki = (char*)d_ws;
    char*  Vi = Ki + KI_B;
    short* Qi = (short*)(Ki + 2 * KI_B);
    float* Lv = (float*)(Ki + 3 * KI_B);
    attn_prep<<<dim3(NTILE), dim3(256), 0, stream>>>(q, k, v, Qi, Ki, Vi);
    attn_out <<<dim3(NTILE), dim3(256), 0, stream>>>(Qi, Ki, Vi, out, Lv);
    attn_wr  <<<dim3(NTILE), dim3(256), 0, stream>>>(Qi, Ki, aw, Lv);
  } else {
    float* Lv = (float*)d_ws;  // 256 KB
    attn_out_fb<<<dim3(NTILE), dim3(256), 0, stream>>>(q, k, v, out, Lv);
    attn_wr_fb <<<dim3(NTILE), dim3(256), 0, stream>>>(q, k, aw, Lv);
  }
}

// Round 4
// 234.920 us; speedup vs baseline: 1.1030x; 1.1030x over previous
//
#include <hip/hip_runtime.h>
#include <hip/hip_bf16.h>

namespace {

constexpr int S  = 2048;
constexpr int D  = 64;
constexpr int NHEAD = 32;        // B*H
constexpr int QT = 64;           // q rows per block (4 waves x 16)
constexpr int NT = 64;           // k rows per chunk
constexpr int NCH = S / NT;      // 32
constexpr int NTILE = NHEAD * NCH;   // 1024
constexpr int TILE_B = 64 * 128;     // 8 KB bf16 tile image

using bf16x8 = __attribute__((ext_vector_type(8))) short;
using bf16x4 = __attribute__((ext_vector_type(4))) short;
using f32x4  = __attribute__((ext_vector_type(4))) float;

__device__ __forceinline__ short f2bf(float f) {
  union { float f; unsigned u; } x; x.f = f;
  unsigned r = x.u + 0x7fffu + ((x.u >> 16) & 1u);
  return (short)(r >> 16);
}

__device__ __forceinline__ void gload16(const void* g, void* l) {
  __builtin_amdgcn_global_load_lds(
      (const __attribute__((address_space(1))) unsigned int*)g,
      (__attribute__((address_space(3))) unsigned int*)l, 16, 0, 0);
}

// K tile layout (LDS or image): row n, byte = n*128 + ((2d) ^ ((n&7)<<4))
// V^T tile layout: row d, permuted col'(key) = 32*(key>>5) + 8*((key>>2)&3)
//   + 4*((key>>4)&1) + (key&3); byte = d*128 + ((2*col') ^ ((d&7)<<4))
// PV kslot map: MFMA m, kslot 8g+j -> key 32m + 16*(j>>2) + 4g + (j&3),
// so pa[m] = {e[2m][0..3], e[2m+1][0..3]} and vb is one contiguous b128 read.

// ============================================================================
// Prep: build swizzled bf16 K images (and V^T images when DO_V).
// ============================================================================
template<bool DO_V>
__global__ __launch_bounds__(256) void attn_prep(
    const float* __restrict__ K, const float* __restrict__ V,
    char* __restrict__ Ki, char* __restrict__ Vi)
{
  const int bid = blockIdx.x, head = bid >> 5, nt = bid & 31;
  const int tid = threadIdx.x;
  const size_t sbase = (size_t)head * S * D + (size_t)nt * NT * D;
#pragma unroll
  for (int it = 0; it < 2; ++it) {
    const int w = tid + it * 256, n = w >> 3, seg = w & 7;
    const float* kp = K + sbase + n * D + seg * 8;
    float4 a = ((const float4*)kp)[0], b = ((const float4*)kp)[1];
    bf16x8 h;
    h[0]=f2bf(a.x); h[1]=f2bf(a.y); h[2]=f2bf(a.z); h[3]=f2bf(a.w);
    h[4]=f2bf(b.x); h[5]=f2bf(b.y); h[6]=f2bf(b.z); h[7]=f2bf(b.w);
    *(bf16x8*)(Ki + (size_t)bid * TILE_B + n * 128 + ((seg * 16) ^ ((n & 7) << 4))) = h;
  }
  if constexpr (DO_V) {
    const int tbr = tid >> 4, tbc = tid & 15;
    const float* vp = V + sbase + (size_t)(tbr * 4) * D + tbc * 4;
    float4 r0 = *(const float4*)vp,       r1 = *(const float4*)(vp + D);
    float4 r2 = *(const float4*)(vp+2*D), r3 = *(const float4*)(vp + 3*D);
    const int cp = 64 * (tbr >> 3) + 16 * (tbr & 3) + 8 * ((tbr >> 2) & 1);
#pragma unroll
    for (int dl = 0; dl < 4; ++dl) {
      int d = tbc * 4 + dl;
      bf16x4 w;
      w[0] = f2bf(((const float*)&r0)[dl]);
      w[1] = f2bf(((const float*)&r1)[dl]);
      w[2] = f2bf(((const float*)&r2)[dl]);
      w[3] = f2bf(((const float*)&r3)[dl]);
      *(bf16x4*)(Vi + (size_t)bid * TILE_B + d * 128 + (cp ^ ((d & 7) << 4))) = w;
    }
  }
}

// ============================================================================
// Kernel 1: flash out + linv. Swapped QK^T -> exp -> in-register P repack ->
// PV (no P-LDS, no mid-chunk LDS drain). TIER: 0 = VALU-convert K&V,
// 1 = gload K image + VALU V, 2 = gload K & V images.
// ============================================================================
template<int TIER>
__global__ __launch_bounds__(256) void attn_out_k(
    const float* __restrict__ Q, const float* __restrict__ K,
    const float* __restrict__ V, const char* __restrict__ Ki,
    const char* __restrict__ Vi, float* __restrict__ Out,
    float* __restrict__ Lv)
{
  __shared__ char Kl[2][TILE_B];
  __shared__ char Vt[2][TILE_B];

  const int tid = threadIdx.x, wave = tid >> 6, lane = tid & 63;
  const int g = lane >> 4, r = lane & 15;
  int wg = blockIdx.x;
  if constexpr (TIER >= 1) wg = ((wg & 7) << 7) | (wg >> 3);  // XCD swizzle
  const int head = wg >> 5, qt = wg & 31;
  const int qrow0 = qt * QT + wave * 16;
  const size_t base = (size_t)head * S * D;

  // Q as B-frag: col n=r -> q=qrow0+r, kslot 8g+j -> d=f*32+8g+j; prescaled
  bf16x8 qb[2];
  {
    const float* qp = Q + base + (size_t)(qrow0 + r) * D + g * 8;
#pragma unroll
    for (int f = 0; f < 2; ++f) {
      float4 a = *(const float4*)(qp + f * 32);
      float4 b = *(const float4*)(qp + f * 32 + 4);
      bf16x8 t;
      t[0]=f2bf(a.x*.125f); t[1]=f2bf(a.y*.125f); t[2]=f2bf(a.z*.125f); t[3]=f2bf(a.w*.125f);
      t[4]=f2bf(b.x*.125f); t[5]=f2bf(b.y*.125f); t[6]=f2bf(b.z*.125f); t[7]=f2bf(b.w*.125f);
      qb[f] = t;
    }
  }

  const int sn = tid >> 2, sseg = tid & 3;
  const int tbr = tid >> 4, tbc = tid & 15;
  const float* kp0 = K + base + (size_t)sn * D + sseg * 16;
  const float* vp0 = V + base + (size_t)(tbr * 4) * D + tbc * 4;
  const char* kt0 = Ki + (size_t)(head * NCH) * TILE_B + wave * 2048 + lane * 16;
  const char* vt0 = Vi + (size_t)(head * NCH) * TILE_B + wave * 2048 + lane * 16;

  float4 kr[4], vr[4];
  auto loadK_regs = [&](int nt) {
    const float* kp = kp0 + (size_t)nt * NT * D;
    kr[0]=((const float4*)kp)[0]; kr[1]=((const float4*)kp)[1];
    kr[2]=((const float4*)kp)[2]; kr[3]=((const float4*)kp)[3];
  };
  auto loadV_regs = [&](int nt) {
    const float* vp = vp0 + (size_t)nt * NT * D;
    vr[0]=*(const float4*)(vp);       vr[1]=*(const float4*)(vp + D);
    vr[2]=*(const float4*)(vp + 2*D); vr[3]=*(const float4*)(vp + 3*D);
  };
  auto stageK_valu = [&](int buf) {
    bf16x8 h0, h1;
    h0[0]=f2bf(kr[0].x); h0[1]=f2bf(kr[0].y); h0[2]=f2bf(kr[0].z); h0[3]=f2bf(kr[0].w);
    h0[4]=f2bf(kr[1].x); h0[5]=f2bf(kr[1].y); h0[6]=f2bf(kr[1].z); h0[7]=f2bf(kr[1].w);
    h1[0]=f2bf(kr[2].x); h1[1]=f2bf(kr[2].y); h1[2]=f2bf(kr[2].z); h1[3]=f2bf(kr[2].w);
    h1[4]=f2bf(kr[3].x); h1[5]=f2bf(kr[3].y); h1[6]=f2bf(kr[3].z); h1[7]=f2bf(kr[3].w);
    char* rowp = Kl[buf] + sn * 128;
    *(bf16x8*)(rowp + ((sseg * 32)      ^ ((sn & 7) << 4))) = h0;
    *(bf16x8*)(rowp + ((sseg * 32 + 16) ^ ((sn & 7) << 4))) = h1;
  };
  auto stageV_valu = [&](int buf) {
    const int cp = 64 * (tbr >> 3) + 16 * (tbr & 3) + 8 * ((tbr >> 2) & 1);
#pragma unroll
    for (int dl = 0; dl < 4; ++dl) {
      int d = tbc * 4 + dl;
      bf16x4 w;
      w[0]=f2bf(((const float*)&vr[0])[dl]);
      w[1]=f2bf(((const float*)&vr[1])[dl]);
      w[2]=f2bf(((const float*)&vr[2])[dl]);
      w[3]=f2bf(((const float*)&vr[3])[dl]);
      *(bf16x4*)(Vt[buf] + d * 128 + (cp ^ ((d & 7) << 4))) = w;
    }
  };
  auto gloadK = [&](int buf, int nt) {
    const char* ks = kt0 + (size_t)nt * TILE_B;
    char* kd = Kl[buf] + wave * 2048;
    gload16(ks, kd); gload16(ks + 1024, kd + 1024);
  };
  auto gloadV = [&](int buf, int nt) {
    const char* vs = vt0 + (size_t)nt * TILE_B;
    char* vd = Vt[buf] + wave * 2048;
    gload16(vs, vd); gload16(vs + 1024, vd + 1024);
  };

  // prologue: fill buffer 0
  if constexpr (TIER == 0) { loadK_regs(0); loadV_regs(0); stageK_valu(0); stageV_valu(0); }
  if constexpr (TIER == 1) { gloadK(0, 0); loadV_regs(0); stageV_valu(0); }
  if constexpr (TIER == 2) { gloadK(0, 0); gloadV(0, 0); }

  float lsum = 0.f;
  f32x4 acc[4];
#pragma unroll
  for (int dt = 0; dt < 4; ++dt) acc[dt] = f32x4{0.f, 0.f, 0.f, 0.f};

  for (int nt = 0; nt < NCH; ++nt) {
    const int cur = nt & 1;
    __syncthreads();   // drains vmcnt/lgkm: buf[cur] ready, buf[cur^1] free
    if (nt + 1 < NCH) {
      if constexpr (TIER == 0) { loadK_regs(nt + 1); loadV_regs(nt + 1); }
      if constexpr (TIER == 1) { gloadK(cur ^ 1, nt + 1); loadV_regs(nt + 1); }
      if constexpr (TIER == 2) { gloadK(cur ^ 1, nt + 1); gloadV(cur ^ 1, nt + 1); }
    }

    // QK^T swapped: A=K (row m=r -> key 16t+r), B=Q. C: lane holds q=r,
    // keys 16t+4g+j in s[t][j].
    f32x4 s[4];
#pragma unroll
    for (int t = 0; t < 4; ++t) s[t] = f32x4{0.f, 0.f, 0.f, 0.f};
#pragma unroll
    for (int f = 0; f < 2; ++f) {
#pragma unroll
      for (int t = 0; t < 4; ++t) {
        bf16x8 ka = *(const bf16x8*)(Kl[cur] + (t * 16 + r) * 128 +
                        ((f * 64 + g * 16) ^ ((r & 7) << 4)));
        s[t] = __builtin_amdgcn_mfma_f32_16x16x32_bf16(ka, qb[f], s[t], 0, 0, 0);
      }
    }

    float e[4][4];
#pragma unroll
    for (int t = 0; t < 4; ++t)
#pragma unroll
      for (int j = 0; j < 4; ++j) { e[t][j] = __expf(s[t][j]); lsum += e[t][j]; }

    // in-register P repack: pa[m] kslot 8g+j -> key 32m+16*(j>>2)+4g+(j&3)
    bf16x8 pa0, pa1;
    pa0[0]=f2bf(e[0][0]); pa0[1]=f2bf(e[0][1]); pa0[2]=f2bf(e[0][2]); pa0[3]=f2bf(e[0][3]);
    pa0[4]=f2bf(e[1][0]); pa0[5]=f2bf(e[1][1]); pa0[6]=f2bf(e[1][2]); pa0[7]=f2bf(e[1][3]);
    pa1[0]=f2bf(e[2][0]); pa1[1]=f2bf(e[2][1]); pa1[2]=f2bf(e[2][2]); pa1[3]=f2bf(e[2][3]);
    pa1[4]=f2bf(e[3][0]); pa1[5]=f2bf(e[3][1]); pa1[6]=f2bf(e[3][2]); pa1[7]=f2bf(e[3][3]);

    // PV: B=V^T permuted image; vb elems j -> V[key 32m+16(j>>2)+4g+(j&3)][dt*16+r]
#pragma unroll
    for (int m = 0; m < 2; ++m) {
#pragma unroll
      for (int dt = 0; dt < 4; ++dt) {
        bf16x8 vb = *(const bf16x8*)(Vt[cur] + (dt * 16 + r) * 128 +
                        ((m * 64 + g * 16) ^ ((r & 7) << 4)));
        acc[dt] = __builtin_amdgcn_mfma_f32_16x16x32_bf16(m ? pa1 : pa0, vb, acc[dt], 0, 0, 0);
      }
    }

    if (nt + 1 < NCH) {
      if constexpr (TIER == 0) { stageK_valu(cur ^ 1); stageV_valu(cur ^ 1); }
      if constexpr (TIER == 1) { stageV_valu(cur ^ 1); }
    }
  }

  // lsum: lane holds partial for q=qrow0+r over its 16 keys -> sum g-groups
  lsum += __shfl_xor(lsum, 16, 64);
  lsum += __shfl_xor(lsum, 32, 64);
  float linv = 1.f / lsum;
  float linv4[4];
#pragma unroll
  for (int j = 0; j < 4; ++j) linv4[j] = __shfl(linv, 20 * g + j, 64);  // lane 16g+(4g+j)

  // PV C/D: lane holds O[q=qrow0+4g+j][d=dt*16+r]
#pragma unroll
  for (int dt = 0; dt < 4; ++dt)
#pragma unroll
    for (int j = 0; j < 4; ++j)
      Out[base + (size_t)(qrow0 + 4 * g + j) * D + dt * 16 + r] = acc[dt][j] * linv4[j];

  if (lane < 16) Lv[head * S + qrow0 + lane] = linv;
}

// ============================================================================
// Kernel 2 (image): attn-weight streamer, K A-frags direct from Ki (L2).
// ============================================================================
__global__ __launch_bounds__(256) void attn_wr_img(
    const float* __restrict__ Q, const char* __restrict__ Ki,
    float* __restrict__ Aw, const float* __restrict__ Lv)
{
  const int tid = threadIdx.x, wave = tid >> 6, lane = tid & 63;
  const int g = lane >> 4, r = lane & 15;
  const int b = blockIdx.x;
  const int wg = ((b & 7) << 7) | (b >> 3);
  const int head = wg >> 5, qt = wg & 31;
  const int q = qt * QT + wave * 16 + r;

  bf16x8 qb[2];
  {
    const float* qp = Q + (size_t)head * S * D + (size_t)q * D + g * 8;
#pragma unroll
    for (int f = 0; f < 2; ++f) {
      float4 a = *(const float4*)(qp + f * 32);
      float4 bb = *(const float4*)(qp + f * 32 + 4);
      bf16x8 t;
      t[0]=f2bf(a.x*.125f); t[1]=f2bf(a.y*.125f); t[2]=f2bf(a.z*.125f); t[3]=f2bf(a.w*.125f);
      t[4]=f2bf(bb.x*.125f); t[5]=f2bf(bb.y*.125f); t[6]=f2bf(bb.z*.125f); t[7]=f2bf(bb.w*.125f);
      qb[f] = t;
    }
  }
  const float linv = Lv[head * S + q];
  float* arow = Aw + (size_t)head * S * S + (size_t)q * S;

  int loff[8];
#pragma unroll
  for (int f = 0; f < 2; ++f)
#pragma unroll
    for (int t = 0; t < 4; ++t)
      loff[f * 4 + t] = (t * 16 + r) * 128 + ((f * 64 + g * 16) ^ ((r & 7) << 4));
  const char* kbase = Ki + (size_t)(head * NCH) * TILE_B;

  bf16x8 fa[8], fb[8];
  auto load8 = [&](bf16x8 (&fr)[8], int nt) {
    const char* p = kbase + (size_t)nt * TILE_B;
#pragma unroll
    for (int i = 0; i < 8; ++i) fr[i] = *(const bf16x8*)(p + loff[i]);
  };
  auto comp = [&](const bf16x8 (&fr)[8], int nt) {
    f32x4 s[4];
#pragma unroll
    for (int t = 0; t < 4; ++t) s[t] = f32x4{0.f, 0.f, 0.f, 0.f};
#pragma unroll
    for (int f = 0; f < 2; ++f)
#pragma unroll
      for (int t = 0; t < 4; ++t)
        s[t] = __builtin_amdgcn_mfma_f32_16x16x32_bf16(fr[f * 4 + t], qb[f], s[t], 0, 0, 0);
#pragma unroll
    for (int t = 0; t < 4; ++t) {
      float4 pv;
      pv.x = __expf(s[t][0]) * linv;
      pv.y = __expf(s[t][1]) * linv;
      pv.z = __expf(s[t][2]) * linv;
      pv.w = __expf(s[t][3]) * linv;
      *(float4*)(arow + nt * NT + t * 16 + 4 * g) = pv;
    }
  };

  load8(fa, 0);
  for (int nt = 0; nt < NCH; nt += 2) {
    load8(fb, nt + 1);
    comp(fa, nt);
    if (nt + 2 < NCH) load8(fa, nt + 2);
    comp(fb, nt + 1);
  }
}

// ============================================================================
// Kernel 2 (fallback): LDS-staged streamer (round-2 verified).
// ============================================================================
__global__ __launch_bounds__(256) void attn_wr_fb(
    const float* __restrict__ Q, const float* __restrict__ K,
    float* __restrict__ Aw, const float* __restrict__ Lv)
{
  __shared__ short Klb[2][64 * 64];
  const int tid = threadIdx.x, wave = tid >> 6, lane = tid & 63;
  const int g = lane >> 4, r = lane & 15;
  const int head = blockIdx.x >> 5, qt = blockIdx.x & 31;
  const size_t base = (size_t)head * S * D;
  float* att = Aw + (size_t)head * S * S;
  const int q = qt * QT + wave * 16 + r;
  bf16x8 qb[2];
  {
    const float* qp = Q + base + (size_t)q * D + g * 8;
#pragma unroll
    for (int f = 0; f < 2; ++f) {
      float4 a = *(const float4*)(qp + f * 32);
      float4 bb = *(const float4*)(qp + f * 32 + 4);
      bf16x8 t;
      t[0]=f2bf(a.x*.125f); t[1]=f2bf(a.y*.125f); t[2]=f2bf(a.z*.125f); t[3]=f2bf(a.w*.125f);
      t[4]=f2bf(bb.x*.125f); t[5]=f2bf(bb.y*.125f); t[6]=f2bf(bb.z*.125f); t[7]=f2bf(bb.w*.125f);
      qb[f] = t;
    }
  }
  const float linv = Lv[head * S + q];
  float* arow = att + (size_t)q * S;
  const int sn = tid >> 2, sseg = tid & 3;
  const float* kp0 = K + base + (size_t)sn * D + sseg * 16;
  float4 kr[4];
  auto loadK = [&](int nt) {
    const float* kp = kp0 + (size_t)nt * NT * D;
    kr[0]=((const float4*)kp)[0]; kr[1]=((const float4*)kp)[1];
    kr[2]=((const float4*)kp)[2]; kr[3]=((const float4*)kp)[3];
  };
  auto stageK = [&](int buf) {
    bf16x8 h0, h1;
    h0[0]=f2bf(kr[0].x); h0[1]=f2bf(kr[0].y); h0[2]=f2bf(kr[0].z); h0[3]=f2bf(kr[0].w);
    h0[4]=f2bf(kr[1].x); h0[5]=f2bf(kr[1].y); h0[6]=f2bf(kr[1].z); h0[7]=f2bf(kr[1].w);
    h1[0]=f2bf(kr[2].x); h1[1]=f2bf(kr[2].y); h1[2]=f2bf(kr[2].z); h1[3]=f2bf(kr[2].w);
    h1[4]=f2bf(kr[3].x); h1[5]=f2bf(kr[3].y); h1[6]=f2bf(kr[3].z); h1[7]=f2bf(kr[3].w);
    char* rowp = (char*)Klb[buf] + sn * 128;
    *(bf16x8*)(rowp + ((sseg * 32)      ^ ((sn & 7) << 4))) = h0;
    *(bf16x8*)(rowp + ((sseg * 32 + 16) ^ ((sn & 7) << 4))) = h1;
  };
  loadK(0); stageK(0);
  for (int nt = 0; nt < NCH; ++nt) {
    const int cur = nt & 1;
    __syncthreads();
    if (nt + 1 < NCH) loadK(nt + 1);
    f32x4 s[4];
#pragma unroll
    for (int t = 0; t < 4; ++t) s[t] = f32x4{0.f,0.f,0.f,0.f};
#pragma unroll
    for (int f = 0; f < 2; ++f)
#pragma unroll
      for (int t = 0; t < 4; ++t) {
        bf16x8 ka = *(const bf16x8*)((char*)Klb[cur] + (t*16+r)*128 + ((f*64+g*16) ^ ((r&7)<<4)));
        s[t] = __builtin_amdgcn_mfma_f32_16x16x32_bf16(ka, qb[f], s[t], 0, 0, 0);
      }
#pragma unroll
    for (int t = 0; t < 4; ++t) {
      float4 pv;
      pv.x = __expf(s[t][0]) * linv;
      pv.y = __expf(s[t][1]) * linv;
      pv.z = __expf(s[t][2]) * linv;
      pv.w = __expf(s[t][3]) * linv;
      *(float4*)(arow + nt * NT + t * 16 + 4 * g) = pv;
    }
    if (nt + 1 < NCH) stageK(cur ^ 1);
  }
}

} // namespace

extern "C" void kernel_launch(void* const* d_in, const int* in_sizes, int n_in,
                              void* d_out, int out_size, void* d_ws, size_t ws_size,
                              hipStream_t stream) {
  const float* q = (const float*)d_in[0];
  const float* k = (const float*)d_in[1];
  const float* v = (const float*)d_in[2];
  float* out = (float*)d_out;
  float* aw  = out + (size_t)NHEAD * S * D;

  const size_t LV_B = (size_t)NHEAD * S * 4;       // 256 KB
  const size_t KI_B = (size_t)NTILE * TILE_B;      // 8 MB
  float* Lv = (float*)d_ws;
  char*  Ki = (char*)d_ws + LV_B;
  char*  Vi = Ki + KI_B;

  if (ws_size >= LV_B + 2 * KI_B) {          // tier 2: K + V images
    attn_prep<true><<<dim3(NTILE), dim3(256), 0, stream>>>(k, v, Ki, Vi);
    attn_out_k<2><<<dim3(NTILE), dim3(256), 0, stream>>>(q, k, v, Ki, Vi, out, Lv);
    attn_wr_img<<<dim3(NTILE), dim3(256), 0, stream>>>(q, Ki, aw, Lv);
  } else if (ws_size >= LV_B + KI_B) {       // tier 1: K image only
    attn_prep<false><<<dim3(NTILE), dim3(256), 0, stream>>>(k, v, Ki, nullptr);
    attn_out_k<1><<<dim3(NTILE), dim3(256), 0, stream>>>(q, k, v, Ki, nullptr, out, Lv);
    attn_wr_img<<<dim3(NTILE), dim3(256), 0, stream>>>(q, Ki, aw, Lv);
  } else {                                   // tier 0: in-kernel converts
    attn_out_k<0><<<dim3(NTILE), dim3(256), 0, stream>>>(q, k, v, nullptr, nullptr, out, Lv);
    attn_wr_fb<<<dim3(NTILE), dim3(256), 0, stream>>>(q, k, aw, Lv);
  }
}